// Round 4
// baseline (3131.256 us; speedup 1.0000x reference)
//
#include <hip/hip_runtime.h>

#define N_NODES     8192
#define N_FEAT      1024
#define N_FILT      4
#define MAXDEG      8

// ---------------------------------------------------------------------------
// Kernel A: filtT[f][v] = (relu(X @ W1^T + b1) @ W2^T + b2)[v][f]
// 1024 blocks x 256 threads; 8 nodes/block, 32 lanes per node
// ---------------------------------------------------------------------------
__global__ __launch_bounds__(256) void filt_kernel(
    const float* __restrict__ X, const float* __restrict__ W1,
    const float* __restrict__ b1, const float* __restrict__ W2,
    const float* __restrict__ b2, float* __restrict__ filtT)
{
    const int node = blockIdx.x * 8 + (threadIdx.x >> 5);
    const int h    = threadIdx.x & 31;
    const float* xr = X  + (size_t)node * N_FEAT;
    const float* wr = W1 + (size_t)h    * N_FEAT;
    float acc = 0.f;
    for (int j = 0; j < N_FEAT; j += 4) {
        float4 xv = *reinterpret_cast<const float4*>(xr + j);
        float4 wv = *reinterpret_cast<const float4*>(wr + j);
        acc += xv.x * wv.x + xv.y * wv.y + xv.z * wv.z + xv.w * wv.w;
    }
    float hv = fmaxf(acc + b1[h], 0.f);
    #pragma unroll
    for (int fo = 0; fo < N_FILT; ++fo) {
        float v = hv * W2[fo * 32 + h];
        for (int off = 16; off; off >>= 1) v += __shfl_xor(v, off, 32);
        if (h == 0) filtT[fo * N_NODES + node] = v + b2[fo];
    }
}

// ---------------------------------------------------------------------------
// Kernel W: wsum[j] = sum_h Wt[h][j] (j=0..7), wsum[8] = sum_h bt[h]
// ---------------------------------------------------------------------------
__global__ void wsum_kernel(const float* __restrict__ Wt,
                            const float* __restrict__ bt,
                            float* __restrict__ wsum)
{
    int t = threadIdx.x;
    if (t < 8) {
        float s = 0.f;
        for (int hh = 0; hh < 64; ++hh) s += Wt[hh * 8 + t];
        wsum[t] = s;
    } else if (t == 8) {
        float s = 0.f;
        for (int hh = 0; hh < 64; ++hh) s += bt[hh];
        wsum[8] = s;
    }
}

// ---------------------------------------------------------------------------
// Kernel R: brute-force stable rank (replaces bitonic sort).
// pos[v] = #{u : val[u] < val[v]  or  (val[u]==val[v] and u < v)}
// 128 blocks (32 per filtration) x 256 threads; each thread ranks one vertex.
// Also scatters order[pos]=v.
// ---------------------------------------------------------------------------
__global__ __launch_bounds__(256) void rank_kernel(
    const float* __restrict__ filtT,
    unsigned short* __restrict__ pos16,
    unsigned short* __restrict__ order16)
{
    const int f     = blockIdx.x >> 5;
    const int v     = ((blockIdx.x & 31) << 8) + threadIdx.x;
    const float myv = filtT[f * N_NODES + v];
    __shared__ float tile[2048];
    int rank = 0;
    for (int t0 = 0; t0 < N_NODES; t0 += 2048) {
        __syncthreads();
        for (int j = threadIdx.x; j < 2048; j += 256)
            tile[j] = filtT[f * N_NODES + t0 + j];
        __syncthreads();
        #pragma unroll 8
        for (int j = 0; j < 2048; ++j) {
            float w = tile[j];
            int   u = t0 + j;
            rank += (w < myv) || (w == myv && u < v);
        }
    }
    pos16[f * N_NODES + v]      = (unsigned short)rank;
    order16[f * N_NODES + rank] = (unsigned short)v;
}

// ---------------------------------------------------------------------------
// Kernel E: static edge filter.  et[f][s*8+k] = min(pos[dst[order[s]*8+k]], s)
// (invalid / not-yet-activated / self edges all degenerate to s = the vertex)
// ---------------------------------------------------------------------------
__global__ __launch_bounds__(256) void etable_kernel(
    const unsigned short* __restrict__ order16,
    const unsigned short* __restrict__ pos16,
    const int* __restrict__ edge_dst,
    unsigned short* __restrict__ et)
{
    const int f  = blockIdx.x >> 5;
    const int e0 = ((blockIdx.x & 31) << 11);
    for (int i = threadIdx.x; i < 2048; i += 256) {
        int e = e0 + i;
        int s = e >> 3, k = e & 7;
        int v = (int)order16[f * N_NODES + s];
        int u = edge_dst[v * MAXDEG + k];
        int q = (int)pos16[f * N_NODES + u];
        et[(size_t)f * (N_NODES * MAXDEG) + e] = (unsigned short)(q < s ? q : s);
    }
}

// ---------------------------------------------------------------------------
// Kernel B: pure serial union-find sweep (pos-space), one block per filtration.
// All 64 lanes of wave 0 mirror the 8 edge slots (lane&7); per step:
//   - prefetch par[x_next] FIRST (stale value is provably still an ancestor:
//     every parent write stores a then-current root, so chains only move up)
//   - verify/advance from last step's prefetched ancestor to the true root
//   - elder m = 3-op DPP min over the 8 slots (roots <= et <= s)
//   - kills: each slot root p != m -> par[p]=m, dth[p]=s; source compress
//     par[x]=m; lane 0 kills the virgin vertex s when m < s.
// Waves 1-3 only help init/emit.
// ---------------------------------------------------------------------------
__device__ __forceinline__ int row8min(int v) {
    int t = min(v, __builtin_amdgcn_mov_dpp(v, 0xB1, 0xF, 0xF, true));   // quad xor1
    t = min(t, __builtin_amdgcn_mov_dpp(t, 0x4E, 0xF, 0xF, true));       // quad xor2
    t = min(t, __builtin_amdgcn_mov_dpp(t, 0x141, 0xF, 0xF, true));      // half mirror
    return t;
}

#define PSTEP(SV, XC, AC, XN, AN_OUT)                                      \
    {                                                                      \
        AN_OUT = (int)vpar[XN];            /* prefetch for next step */    \
        int p = AC;                                                        \
        for (;;) {                                                         \
            int q = (int)vpar[p];                                          \
            if (__all(q == p)) break;                                      \
            p = q;                                                         \
        }                                                                  \
        int m = row8min(p);                                                \
        if (lane < 8) {                                                    \
            if (p != m) { vpar[p] = (unsigned short)m;                     \
                          s_dth[p] = (unsigned short)(SV); }               \
            vpar[XC] = (unsigned short)m;  /* source compress */           \
        }                                                                  \
        if (lane == 0 && m != (SV)) {      /* virgin vertex dies */        \
            vpar[SV] = (unsigned short)m;                                  \
            s_dth[SV] = (unsigned short)(SV);                              \
        }                                                                  \
    }

__global__ __launch_bounds__(256) void persist_kernel(
    const unsigned short* __restrict__ et,      // [N_FILT][N_NODES*8]
    const unsigned short* __restrict__ pos16,   // [N_FILT][N_NODES]
    unsigned short* __restrict__ death16)       // [N_FILT][N_NODES]
{
    const int f   = blockIdx.x;
    const int tid = threadIdx.x;

    __shared__ unsigned short s_par[N_NODES];
    __shared__ unsigned short s_dth[N_NODES];
    volatile unsigned short* vpar = s_par;

    for (int v = tid; v < N_NODES; v += 256) { s_par[v] = (unsigned short)v; s_dth[v] = 0; }
    __syncthreads();

    if (tid < 64) {
        const int lane = tid;
        const unsigned short* etf = et + (size_t)f * (N_NODES * MAXDEG) + (lane & 7);
        int b0 = (int)etf[0], b1 = (int)etf[8], b2 = (int)etf[16], b3 = (int)etf[24];
        int a0 = b0, a1, a2, a3;    // par == identity at start
        for (int s = 0; s < N_NODES; s += 4) {
            const int rbase = (s + 4 < N_NODES) ? (s + 4) : 0;  // clamped refill
            PSTEP(s + 0, b0, a0, b1, a1);
            b0 = (int)etf[(rbase + 0) * 8];
            PSTEP(s + 1, b1, a1, b2, a2);
            b1 = (int)etf[(rbase + 1) * 8];
            PSTEP(s + 2, b2, a2, b3, a3);
            b2 = (int)etf[(rbase + 2) * 8];
            PSTEP(s + 3, b3, a3, b0, a0);   // b0 already refilled: next group's slot 0
            b3 = (int)etf[(rbase + 3) * 8];
        }
    }
    __syncthreads();

    // emit deaths by node id; 0 -> N (undying)
    for (int n = tid; n < N_NODES; n += 256) {
        int p = (int)pos16[f * N_NODES + n];
        int d = (int)s_dth[p];
        death16[f * N_NODES + n] = (unsigned short)(d ? d : N_NODES);
    }
}

// ---------------------------------------------------------------------------
// Kernel P: pooled[n] = wsum[8] + sum_f pos_f[n]*wsum[2f] + death_f[n]*wsum[2f+1]
// ---------------------------------------------------------------------------
__global__ __launch_bounds__(256) void pooled_kernel(
    const unsigned short* __restrict__ pos16,
    const unsigned short* __restrict__ death16,
    const float* __restrict__ wsum,
    float* __restrict__ pooled)
{
    int n = blockIdx.x * 256 + threadIdx.x;
    float acc = wsum[8];
    #pragma unroll
    for (int i = 0; i < N_FILT; ++i) {
        acc += (float)pos16[i * N_NODES + n]   * wsum[2 * i + 0]
             + (float)death16[i * N_NODES + n] * wsum[2 * i + 1];
    }
    pooled[n] = acc;
}

// ---------------------------------------------------------------------------
// Kernel C: out[n][f] = X[n][f] + pooled[n]*Wr[f] + br[f]
// ---------------------------------------------------------------------------
__global__ __launch_bounds__(256) void out_kernel(
    const float* __restrict__ X, const float* __restrict__ Wr,
    const float* __restrict__ br, const float* __restrict__ pooled,
    float* __restrict__ out)
{
    const int node = blockIdx.x;
    const float pl = pooled[node];
    const int fb = threadIdx.x * 4;
    const float4 xv = *reinterpret_cast<const float4*>(X + (size_t)node * N_FEAT + fb);
    const float4 wv = *reinterpret_cast<const float4*>(Wr + fb);
    const float4 bv = *reinterpret_cast<const float4*>(br + fb);
    float4 o;
    o.x = xv.x + pl * wv.x + bv.x;
    o.y = xv.y + pl * wv.y + bv.y;
    o.z = xv.z + pl * wv.z + bv.z;
    o.w = xv.w + pl * wv.w + bv.w;
    *reinterpret_cast<float4*>(out + (size_t)node * N_FEAT + fb) = o;
}

// ---------------------------------------------------------------------------
extern "C" void kernel_launch(void* const* d_in, const int* in_sizes, int n_in,
                              void* d_out, int out_size, void* d_ws, size_t ws_size,
                              hipStream_t stream) {
    const float* X  = (const float*)d_in[0];
    const int* edge = (const int*)d_in[1];
    const float* W1 = (const float*)d_in[2];
    const float* b1 = (const float*)d_in[3];
    const float* W2 = (const float*)d_in[4];
    const float* b2 = (const float*)d_in[5];
    const float* Wt = (const float*)d_in[6];
    const float* bt = (const float*)d_in[7];
    const float* Wr = (const float*)d_in[8];
    const float* br = (const float*)d_in[9];

    const int* edge_dst = edge + N_NODES * MAXDEG;  // row 1 of edge_list

    // ws layout (bytes):
    //   [0,        131072)  filtT    f32[4][8192]
    //   [131072,   196608)  pos16    u16[4][8192]
    //   [196608,   262144)  order16  u16[4][8192]   (reused as death16 later)
    //   [262144,   786432)  et       u16[4][65536]
    //   [786432,   786496)  wsum     f32[16]
    //   [786496,   819264)  pooled   f32[8192]
    char* wsb = (char*)d_ws;
    float*          filtT   = (float*)(wsb);
    unsigned short* pos16   = (unsigned short*)(wsb + 131072);
    unsigned short* order16 = (unsigned short*)(wsb + 196608);
    unsigned short* death16 = (unsigned short*)(wsb + 196608); // alias, later
    unsigned short* et      = (unsigned short*)(wsb + 262144);
    float*          wsum    = (float*)(wsb + 786432);
    float*          pooled  = (float*)(wsb + 786496);

    hipLaunchKernelGGL(filt_kernel,  dim3(N_NODES / 8), dim3(256), 0, stream,
                       X, W1, b1, W2, b2, filtT);
    hipLaunchKernelGGL(wsum_kernel,  dim3(1), dim3(64), 0, stream, Wt, bt, wsum);
    hipLaunchKernelGGL(rank_kernel,  dim3(4 * 32), dim3(256), 0, stream,
                       filtT, pos16, order16);
    hipLaunchKernelGGL(etable_kernel, dim3(4 * 32), dim3(256), 0, stream,
                       order16, pos16, edge_dst, et);
    hipLaunchKernelGGL(persist_kernel, dim3(N_FILT), dim3(256), 0, stream,
                       et, pos16, death16);
    hipLaunchKernelGGL(pooled_kernel, dim3(N_NODES / 256), dim3(256), 0, stream,
                       pos16, death16, wsum, pooled);
    hipLaunchKernelGGL(out_kernel,   dim3(N_NODES), dim3(256), 0, stream,
                       X, Wr, br, pooled, (float*)d_out);
}

// Round 5
// 2670.541 us; speedup vs baseline: 1.1725x; 1.1725x over previous
//
#include <hip/hip_runtime.h>

#define N_NODES     8192
#define N_FEAT      1024
#define N_FILT      4
#define MAXDEG      8

// ---------------------------------------------------------------------------
// Kernel A: filtT[f][v] = (relu(X @ W1^T + b1) @ W2^T + b2)[v][f]
// ---------------------------------------------------------------------------
__global__ __launch_bounds__(256) void filt_kernel(
    const float* __restrict__ X, const float* __restrict__ W1,
    const float* __restrict__ b1, const float* __restrict__ W2,
    const float* __restrict__ b2, float* __restrict__ filtT)
{
    const int node = blockIdx.x * 8 + (threadIdx.x >> 5);
    const int h    = threadIdx.x & 31;
    const float* xr = X  + (size_t)node * N_FEAT;
    const float* wr = W1 + (size_t)h    * N_FEAT;
    float acc = 0.f;
    for (int j = 0; j < N_FEAT; j += 4) {
        float4 xv = *reinterpret_cast<const float4*>(xr + j);
        float4 wv = *reinterpret_cast<const float4*>(wr + j);
        acc += xv.x * wv.x + xv.y * wv.y + xv.z * wv.z + xv.w * wv.w;
    }
    float hv = fmaxf(acc + b1[h], 0.f);
    #pragma unroll
    for (int fo = 0; fo < N_FILT; ++fo) {
        float v = hv * W2[fo * 32 + h];
        for (int off = 16; off; off >>= 1) v += __shfl_xor(v, off, 32);
        if (h == 0) filtT[fo * N_NODES + node] = v + b2[fo];
    }
}

// ---------------------------------------------------------------------------
// Kernel W: wsum[j] = sum_h Wt[h][j] (j=0..7), wsum[8] = sum_h bt[h]
// ---------------------------------------------------------------------------
__global__ void wsum_kernel(const float* __restrict__ Wt,
                            const float* __restrict__ bt,
                            float* __restrict__ wsum)
{
    int t = threadIdx.x;
    if (t < 8) {
        float s = 0.f;
        for (int hh = 0; hh < 64; ++hh) s += Wt[hh * 8 + t];
        wsum[t] = s;
    } else if (t == 8) {
        float s = 0.f;
        for (int hh = 0; hh < 64; ++hh) s += bt[hh];
        wsum[8] = s;
    }
}

// ---------------------------------------------------------------------------
// Kernel R: brute-force stable rank.  pos[v] = #{u : (val,id) < (val,id)_v}
// ---------------------------------------------------------------------------
__global__ __launch_bounds__(256) void rank_kernel(
    const float* __restrict__ filtT,
    unsigned short* __restrict__ pos16,
    unsigned short* __restrict__ order16)
{
    const int f     = blockIdx.x >> 5;
    const int v     = ((blockIdx.x & 31) << 8) + threadIdx.x;
    const float myv = filtT[f * N_NODES + v];
    __shared__ float tile[2048];
    int rank = 0;
    for (int t0 = 0; t0 < N_NODES; t0 += 2048) {
        __syncthreads();
        for (int j = threadIdx.x; j < 2048; j += 256)
            tile[j] = filtT[f * N_NODES + t0 + j];
        __syncthreads();
        #pragma unroll 8
        for (int j = 0; j < 2048; ++j) {
            float w = tile[j];
            int   u = t0 + j;
            rank += (w < myv) || (w == myv && u < v);
        }
    }
    pos16[f * N_NODES + v]      = (unsigned short)rank;
    order16[f * N_NODES + rank] = (unsigned short)v;
}

// ---------------------------------------------------------------------------
// Kernel E: static edge filter.  et[f][s*8+k] = min(pos[dst[order[s]*8+k]], s)
// ---------------------------------------------------------------------------
__global__ __launch_bounds__(256) void etable_kernel(
    const unsigned short* __restrict__ order16,
    const unsigned short* __restrict__ pos16,
    const int* __restrict__ edge_dst,
    unsigned short* __restrict__ et)
{
    const int f  = blockIdx.x >> 5;
    const int e0 = ((blockIdx.x & 31) << 11);
    for (int i = threadIdx.x; i < 2048; i += 256) {
        int e = e0 + i;
        int s = e >> 3, k = e & 7;
        int v = (int)order16[f * N_NODES + s];
        int u = edge_dst[v * MAXDEG + k];
        int q = (int)pos16[f * N_NODES + u];
        et[(size_t)f * (N_NODES * MAXDEG) + e] = (unsigned short)(q < s ? q : s);
    }
}

// ---------------------------------------------------------------------------
// Kernel B: serial union-find sweep, packed pd[v] = par | (dth<<16) in LDS.
// Wave 0 runs the 8192-step sweep (8 edge slots mirrored across 8 rows);
// waves 1-3 do guarded background path compression of dead chains.
//
// Safety invariants:
//  - parent pointers only ever move to ancestors (kills/compress target
//    current roots / ancestors), so a STALE par value is a valid find start.
//  - dth is write-once: only roots die; non-root => already dead => dth fixed.
//  - serial compress only when x was dead at prefetch (dx!=0): cannot
//    resurrect; alive-root x is handled by the kill / vertex writes.
//  - compressor waves only rewrite pd[v] when BOTH v and par[v] are dead:
//    never touches a live root, dth preserved from immutable dead value.
// ---------------------------------------------------------------------------
__device__ __forceinline__ int row8min(int v) {
    int t = min(v, __builtin_amdgcn_mov_dpp(v, 0xB1, 0xF, 0xF, true));   // quad xor1
    t = min(t, __builtin_amdgcn_mov_dpp(t, 0x4E, 0xF, 0xF, true));       // quad xor2
    t = min(t, __builtin_amdgcn_mov_dpp(t, 0x141, 0xF, 0xF, true));      // half mirror
    return t;
}

__device__ __forceinline__ void pstep(volatile unsigned int* vpd, int lane,
                                      int sv, int x, unsigned kc,
                                      int xn, unsigned& kn)
{
    kn = vpd[xn];                          // prefetch next step's pd[x] (stale ok)
    int p = (int)(kc & 0xffffu);           // stale ancestor of x: safe start
    for (;;) {
        int q = (int)(vpd[p] & 0xffffu);
        if (__all(q == p)) break;
        p = q;
    }
    int m = row8min(p);                    // elder of the merge set (m <= p <= x <= sv)
    unsigned dx = kc >> 16;
    if (lane < 8) {
        if (dx != 0u) vpd[x] = (unsigned)m | (dx << 16);              // compress dead x
        if (p != m)   vpd[p] = (unsigned)m | ((unsigned)sv << 16);    // kill root p
        if (lane == 0 && m != sv)                                     // virgin vertex dies
            vpd[sv] = (unsigned)m | ((unsigned)sv << 16);
    }
}

__global__ __launch_bounds__(256) void persist_kernel(
    const unsigned short* __restrict__ et,      // [N_FILT][N_NODES*8]
    const unsigned short* __restrict__ pos16,   // [N_FILT][N_NODES]
    unsigned short* __restrict__ death16)       // [N_FILT][N_NODES]
{
    const int f   = blockIdx.x;
    const int tid = threadIdx.x;

    __shared__ unsigned int s_pd[N_NODES];      // 32 KB packed par|dth
    __shared__ int s_done;
    volatile unsigned int* vpd = s_pd;
    volatile int* vdone = &s_done;

    for (int v = tid; v < N_NODES; v += 256) s_pd[v] = (unsigned)v;  // par=v, dth=0
    if (tid == 0) s_done = 0;
    __syncthreads();

    if (tid < 64) {
        const int lane = tid;
        const unsigned short* etf = et + (size_t)f * (N_NODES * MAXDEG) + (lane & 7);
        int xa = (int)etf[0], xb = (int)etf[8], xc = (int)etf[16], xd = (int)etf[24];
        unsigned ka = vpd[xa], kb = vpd[xb], kc2 = vpd[xc], kd = vpd[xd];
        for (int s = 0; s < N_NODES; s += 4) {
            const int rb = (s + 4 < N_NODES) ? (s + 4) : 0;   // clamped refill
            pstep(vpd, lane, s + 0, xa, ka,  xb, kb);  xa = (int)etf[(rb + 0) * 8];
            pstep(vpd, lane, s + 1, xb, kb,  xc, kc2); xb = (int)etf[(rb + 1) * 8];
            pstep(vpd, lane, s + 2, xc, kc2, xd, kd);  xc = (int)etf[(rb + 2) * 8];
            pstep(vpd, lane, s + 3, xd, kd,  xa, ka);  xd = (int)etf[(rb + 3) * 8];
        }
        if (lane == 0) *vdone = 1;
    } else {
        // background compression of dead chains (both-dead guard: race-free)
        while (!*vdone) {
            for (int v = tid - 64; v < N_NODES; v += 192) {
                unsigned kv = vpd[v];
                if ((kv >> 16) != 0u) {                  // v dead (stable)
                    int pv = (int)(kv & 0xffffu);
                    unsigned kp = vpd[pv];
                    if ((kp >> 16) != 0u)                // parent dead too -> hop
                        vpd[v] = (kp & 0xffffu) | (kv & 0xffff0000u);
                }
            }
            __builtin_amdgcn_s_sleep(2);
        }
    }
    __syncthreads();

    // emit deaths by node id; 0 -> N (undying)
    for (int n = tid; n < N_NODES; n += 256) {
        int p = (int)pos16[f * N_NODES + n];
        int d = (int)(s_pd[p] >> 16);
        death16[f * N_NODES + n] = (unsigned short)(d ? d : N_NODES);
    }
}

// ---------------------------------------------------------------------------
// Kernel P: pooled[n] = wsum[8] + sum_f pos_f[n]*wsum[2f] + death_f[n]*wsum[2f+1]
// ---------------------------------------------------------------------------
__global__ __launch_bounds__(256) void pooled_kernel(
    const unsigned short* __restrict__ pos16,
    const unsigned short* __restrict__ death16,
    const float* __restrict__ wsum,
    float* __restrict__ pooled)
{
    int n = blockIdx.x * 256 + threadIdx.x;
    float acc = wsum[8];
    #pragma unroll
    for (int i = 0; i < N_FILT; ++i) {
        acc += (float)pos16[i * N_NODES + n]   * wsum[2 * i + 0]
             + (float)death16[i * N_NODES + n] * wsum[2 * i + 1];
    }
    pooled[n] = acc;
}

// ---------------------------------------------------------------------------
// Kernel C: out[n][f] = X[n][f] + pooled[n]*Wr[f] + br[f]
// ---------------------------------------------------------------------------
__global__ __launch_bounds__(256) void out_kernel(
    const float* __restrict__ X, const float* __restrict__ Wr,
    const float* __restrict__ br, const float* __restrict__ pooled,
    float* __restrict__ out)
{
    const int node = blockIdx.x;
    const float pl = pooled[node];
    const int fb = threadIdx.x * 4;
    const float4 xv = *reinterpret_cast<const float4*>(X + (size_t)node * N_FEAT + fb);
    const float4 wv = *reinterpret_cast<const float4*>(Wr + fb);
    const float4 bv = *reinterpret_cast<const float4*>(br + fb);
    float4 o;
    o.x = xv.x + pl * wv.x + bv.x;
    o.y = xv.y + pl * wv.y + bv.y;
    o.z = xv.z + pl * wv.z + bv.z;
    o.w = xv.w + pl * wv.w + bv.w;
    *reinterpret_cast<float4*>(out + (size_t)node * N_FEAT + fb) = o;
}

// ---------------------------------------------------------------------------
extern "C" void kernel_launch(void* const* d_in, const int* in_sizes, int n_in,
                              void* d_out, int out_size, void* d_ws, size_t ws_size,
                              hipStream_t stream) {
    const float* X  = (const float*)d_in[0];
    const int* edge = (const int*)d_in[1];
    const float* W1 = (const float*)d_in[2];
    const float* b1 = (const float*)d_in[3];
    const float* W2 = (const float*)d_in[4];
    const float* b2 = (const float*)d_in[5];
    const float* Wt = (const float*)d_in[6];
    const float* bt = (const float*)d_in[7];
    const float* Wr = (const float*)d_in[8];
    const float* br = (const float*)d_in[9];

    const int* edge_dst = edge + N_NODES * MAXDEG;  // row 1 of edge_list

    // ws layout (bytes):
    //   [0,        131072)  filtT    f32[4][8192]
    //   [131072,   196608)  pos16    u16[4][8192]
    //   [196608,   262144)  order16  u16[4][8192]   (reused as death16 later)
    //   [262144,   786432)  et       u16[4][65536]
    //   [786432,   786496)  wsum     f32[16]
    //   [786496,   819264)  pooled   f32[8192]
    char* wsb = (char*)d_ws;
    float*          filtT   = (float*)(wsb);
    unsigned short* pos16   = (unsigned short*)(wsb + 131072);
    unsigned short* order16 = (unsigned short*)(wsb + 196608);
    unsigned short* death16 = (unsigned short*)(wsb + 196608); // alias, later
    unsigned short* et      = (unsigned short*)(wsb + 262144);
    float*          wsum    = (float*)(wsb + 786432);
    float*          pooled  = (float*)(wsb + 786496);

    hipLaunchKernelGGL(filt_kernel,  dim3(N_NODES / 8), dim3(256), 0, stream,
                       X, W1, b1, W2, b2, filtT);
    hipLaunchKernelGGL(wsum_kernel,  dim3(1), dim3(64), 0, stream, Wt, bt, wsum);
    hipLaunchKernelGGL(rank_kernel,  dim3(4 * 32), dim3(256), 0, stream,
                       filtT, pos16, order16);
    hipLaunchKernelGGL(etable_kernel, dim3(4 * 32), dim3(256), 0, stream,
                       order16, pos16, edge_dst, et);
    hipLaunchKernelGGL(persist_kernel, dim3(N_FILT), dim3(256), 0, stream,
                       et, pos16, death16);
    hipLaunchKernelGGL(pooled_kernel, dim3(N_NODES / 256), dim3(256), 0, stream,
                       pos16, death16, wsum, pooled);
    hipLaunchKernelGGL(out_kernel,   dim3(N_NODES), dim3(256), 0, stream,
                       X, Wr, br, pooled, (float*)d_out);
}

// Round 6
// 918.229 us; speedup vs baseline: 3.4101x; 2.9084x over previous
//
#include <hip/hip_runtime.h>

#define N_NODES     8192
#define N_FEAT      1024
#define N_FILT      4
#define MAXDEG      8
#define BLK         256     // steps per classification block

// ---------------------------------------------------------------------------
// Kernel A: filtT[f][v] = (relu(X @ W1^T + b1) @ W2^T + b2)[v][f]
// ---------------------------------------------------------------------------
__global__ __launch_bounds__(256) void filt_kernel(
    const float* __restrict__ X, const float* __restrict__ W1,
    const float* __restrict__ b1, const float* __restrict__ W2,
    const float* __restrict__ b2, float* __restrict__ filtT)
{
    const int node = blockIdx.x * 8 + (threadIdx.x >> 5);
    const int h    = threadIdx.x & 31;
    const float* xr = X  + (size_t)node * N_FEAT;
    const float* wr = W1 + (size_t)h    * N_FEAT;
    float acc = 0.f;
    for (int j = 0; j < N_FEAT; j += 4) {
        float4 xv = *reinterpret_cast<const float4*>(xr + j);
        float4 wv = *reinterpret_cast<const float4*>(wr + j);
        acc += xv.x * wv.x + xv.y * wv.y + xv.z * wv.z + xv.w * wv.w;
    }
    float hv = fmaxf(acc + b1[h], 0.f);
    #pragma unroll
    for (int fo = 0; fo < N_FILT; ++fo) {
        float v = hv * W2[fo * 32 + h];
        for (int off = 16; off; off >>= 1) v += __shfl_xor(v, off, 32);
        if (h == 0) filtT[fo * N_NODES + node] = v + b2[fo];
    }
}

// ---------------------------------------------------------------------------
// Kernel W: wsum[j] = sum_h Wt[h][j] (j=0..7), wsum[8] = sum_h bt[h]
// ---------------------------------------------------------------------------
__global__ void wsum_kernel(const float* __restrict__ Wt,
                            const float* __restrict__ bt,
                            float* __restrict__ wsum)
{
    int t = threadIdx.x;
    if (t < 8) {
        float s = 0.f;
        for (int hh = 0; hh < 64; ++hh) s += Wt[hh * 8 + t];
        wsum[t] = s;
    } else if (t == 8) {
        float s = 0.f;
        for (int hh = 0; hh < 64; ++hh) s += bt[hh];
        wsum[8] = s;
    }
}

// ---------------------------------------------------------------------------
// Kernel R: brute-force stable rank.  pos[v] = #{u : (val,id) < (val,id)_v}
// ---------------------------------------------------------------------------
__global__ __launch_bounds__(256) void rank_kernel(
    const float* __restrict__ filtT,
    unsigned short* __restrict__ pos16,
    unsigned short* __restrict__ order16)
{
    const int f     = blockIdx.x >> 5;
    const int v     = ((blockIdx.x & 31) << 8) + threadIdx.x;
    const float myv = filtT[f * N_NODES + v];
    __shared__ float tile[2048];
    int rank = 0;
    for (int t0 = 0; t0 < N_NODES; t0 += 2048) {
        __syncthreads();
        for (int j = threadIdx.x; j < 2048; j += 256)
            tile[j] = filtT[f * N_NODES + t0 + j];
        __syncthreads();
        #pragma unroll 8
        for (int j = 0; j < 2048; ++j) {
            float w = tile[j];
            int   u = t0 + j;
            rank += (w < myv) || (w == myv && u < v);
        }
    }
    pos16[f * N_NODES + v]      = (unsigned short)rank;
    order16[f * N_NODES + rank] = (unsigned short)v;
}

// ---------------------------------------------------------------------------
// Kernel E: static edge filter.  et[f][s*8+k] = min(pos[dst[order[s]*8+k]], s)
// ---------------------------------------------------------------------------
__global__ __launch_bounds__(256) void etable_kernel(
    const unsigned short* __restrict__ order16,
    const unsigned short* __restrict__ pos16,
    const int* __restrict__ edge_dst,
    unsigned short* __restrict__ et)
{
    const int f  = blockIdx.x >> 5;
    const int e0 = ((blockIdx.x & 31) << 11);
    for (int i = threadIdx.x; i < 2048; i += 256) {
        int e = e0 + i;
        int s = e >> 3, k = e & 7;
        int v = (int)order16[f * N_NODES + s];
        int u = edge_dst[v * MAXDEG + k];
        int q = (int)pos16[f * N_NODES + u];
        et[(size_t)f * (N_NODES * MAXDEG) + e] = (unsigned short)(q < s ? q : s);
    }
}

// ---------------------------------------------------------------------------
// Kernel B: block-speculative union-find.  pd[v] = par | (dth<<16), par < v
// always (pointers strictly decrease), so chains from position e never cross
// any step >= e.  Per 256-step block:
//   resolve (1 thread/step): snapshot-find roots of the 8 edges; classify
//     isolated / pure / impure.  Pure: pd[s] = root | s<<16 immediately
//     (sound: snapshot merges form a subset of time-s merges, so
//      snapshot-distinct==1  =>  true-distinct-at-s==1).
//   compact impure list (ballot + wave-offset scan), ascending s.
//   wave 0 serially replays ONLY impure steps: ballot-find from snapshot
//     roots -> current roots, elder = 8-lane DPP min, kill writes.
// ---------------------------------------------------------------------------
__device__ __forceinline__ int row8min(int v) {
    int t = min(v, __builtin_amdgcn_mov_dpp(v, 0xB1, 0xF, 0xF, true));   // quad xor1
    t = min(t, __builtin_amdgcn_mov_dpp(t, 0x4E, 0xF, 0xF, true));       // quad xor2
    t = min(t, __builtin_amdgcn_mov_dpp(t, 0x141, 0xF, 0xF, true));      // half mirror
    return t;
}

__global__ __launch_bounds__(256) void persist_kernel(
    const unsigned short* __restrict__ et,      // [N_FILT][N_NODES*8]
    const unsigned short* __restrict__ pos16,   // [N_FILT][N_NODES]
    unsigned short* __restrict__ death16)       // [N_FILT][N_NODES]
{
    const int f    = blockIdx.x;
    const int tid  = threadIdx.x;
    const int lane = tid & 63;
    const int w    = tid >> 6;

    __shared__ unsigned int   s_pd[N_NODES];        // 32 KB packed par|dth
    __shared__ unsigned short s_r16[BLK][8];        // 4 KB snapshot roots
    __shared__ unsigned short s_list[BLK];
    __shared__ int s_wc[4];
    volatile unsigned int* vpd = s_pd;

    for (int v = tid; v < N_NODES; v += 256) s_pd[v] = (unsigned)v;  // par=v, dth=0
    __syncthreads();

    const unsigned short* etf = et + (size_t)f * (N_NODES * MAXDEG);

    for (int lo = 0; lo < N_NODES; lo += BLK) {
        const int s = lo + tid;

        // ---- parallel resolve + classify ----
        uint4 raw = *reinterpret_cast<const uint4*>(etf + (size_t)s * 8);
        int e8[8];
        e8[0] = raw.x & 0xffff; e8[1] = raw.x >> 16;
        e8[2] = raw.y & 0xffff; e8[3] = raw.y >> 16;
        e8[4] = raw.z & 0xffff; e8[5] = raw.z >> 16;
        e8[6] = raw.w & 0xffff; e8[7] = raw.w >> 16;

        unsigned short r[8];
        int first = -1; bool same = true;
        #pragma unroll
        for (int k = 0; k < 8; ++k) {
            int e = e8[k];
            if (e == s) { r[k] = (unsigned short)s; continue; }
            int p = e;
            for (;;) { int q = (int)(vpd[p] & 0xffffu); if (q == p) break; p = q; }
            r[k] = (unsigned short)p;
            if (first < 0) first = p; else if (p != first) same = false;
        }
        bool impure = (first >= 0) && !same;
        if (first >= 0 && same)                       // pure: attach + virgin dies
            vpd[s] = (unsigned)first | ((unsigned)s << 16);
        if (impure) {
            #pragma unroll
            for (int k = 0; k < 8; ++k) s_r16[tid][k] = r[k];
        }

        // ---- compact impure list (ascending s) ----
        unsigned long long bal = __ballot(impure);
        int within = __popcll(bal & ((1ull << lane) - 1ull));
        if (lane == 0) s_wc[w] = __popcll(bal);
        __syncthreads();
        int base = 0;
        for (int i = 0; i < w; ++i) base += s_wc[i];
        int total = s_wc[0] + s_wc[1] + s_wc[2] + s_wc[3];
        if (impure) s_list[base + within] = (unsigned short)tid;
        __syncthreads();

        // ---- serial replay of impure steps only ----
        if (tid < 64) {
            for (int i = 0; i < total; ++i) {
                int t  = (int)s_list[i];
                int sv = lo + t;
                int p  = (int)s_r16[t][lane & 7];
                for (;;) {
                    int q = (int)(vpd[p] & 0xffffu);
                    if (__all(q == p)) break;
                    p = q;
                }
                int m = row8min(p);                   // elder (roots or sv itself)
                if (lane < 8 && p != m)               // kill non-elder roots
                    vpd[p] = (unsigned)m | ((unsigned)sv << 16);
                if (lane == 0)                        // virgin vertex dies (m < sv)
                    vpd[sv] = (unsigned)m | ((unsigned)sv << 16);
            }
        }
        __syncthreads();
    }

    // emit deaths by node id; 0 -> N (undying)
    for (int n = tid; n < N_NODES; n += 256) {
        int p = (int)pos16[f * N_NODES + n];
        int d = (int)(s_pd[p] >> 16);
        death16[f * N_NODES + n] = (unsigned short)(d ? d : N_NODES);
    }
}

// ---------------------------------------------------------------------------
// Kernel P: pooled[n] = wsum[8] + sum_f pos_f[n]*wsum[2f] + death_f[n]*wsum[2f+1]
// ---------------------------------------------------------------------------
__global__ __launch_bounds__(256) void pooled_kernel(
    const unsigned short* __restrict__ pos16,
    const unsigned short* __restrict__ death16,
    const float* __restrict__ wsum,
    float* __restrict__ pooled)
{
    int n = blockIdx.x * 256 + threadIdx.x;
    float acc = wsum[8];
    #pragma unroll
    for (int i = 0; i < N_FILT; ++i) {
        acc += (float)pos16[i * N_NODES + n]   * wsum[2 * i + 0]
             + (float)death16[i * N_NODES + n] * wsum[2 * i + 1];
    }
    pooled[n] = acc;
}

// ---------------------------------------------------------------------------
// Kernel C: out[n][f] = X[n][f] + pooled[n]*Wr[f] + br[f]
// ---------------------------------------------------------------------------
__global__ __launch_bounds__(256) void out_kernel(
    const float* __restrict__ X, const float* __restrict__ Wr,
    const float* __restrict__ br, const float* __restrict__ pooled,
    float* __restrict__ out)
{
    const int node = blockIdx.x;
    const float pl = pooled[node];
    const int fb = threadIdx.x * 4;
    const float4 xv = *reinterpret_cast<const float4*>(X + (size_t)node * N_FEAT + fb);
    const float4 wv = *reinterpret_cast<const float4*>(Wr + fb);
    const float4 bv = *reinterpret_cast<const float4*>(br + fb);
    float4 o;
    o.x = xv.x + pl * wv.x + bv.x;
    o.y = xv.y + pl * wv.y + bv.y;
    o.z = xv.z + pl * wv.z + bv.z;
    o.w = xv.w + pl * wv.w + bv.w;
    *reinterpret_cast<float4*>(out + (size_t)node * N_FEAT + fb) = o;
}

// ---------------------------------------------------------------------------
extern "C" void kernel_launch(void* const* d_in, const int* in_sizes, int n_in,
                              void* d_out, int out_size, void* d_ws, size_t ws_size,
                              hipStream_t stream) {
    const float* X  = (const float*)d_in[0];
    const int* edge = (const int*)d_in[1];
    const float* W1 = (const float*)d_in[2];
    const float* b1 = (const float*)d_in[3];
    const float* W2 = (const float*)d_in[4];
    const float* b2 = (const float*)d_in[5];
    const float* Wt = (const float*)d_in[6];
    const float* bt = (const float*)d_in[7];
    const float* Wr = (const float*)d_in[8];
    const float* br = (const float*)d_in[9];

    const int* edge_dst = edge + N_NODES * MAXDEG;  // row 1 of edge_list

    // ws layout (bytes):
    //   [0,        131072)  filtT    f32[4][8192]
    //   [131072,   196608)  pos16    u16[4][8192]
    //   [196608,   262144)  order16  u16[4][8192]   (reused as death16 later)
    //   [262144,   786432)  et       u16[4][65536]
    //   [786432,   786496)  wsum     f32[16]
    //   [786496,   819264)  pooled   f32[8192]
    char* wsb = (char*)d_ws;
    float*          filtT   = (float*)(wsb);
    unsigned short* pos16   = (unsigned short*)(wsb + 131072);
    unsigned short* order16 = (unsigned short*)(wsb + 196608);
    unsigned short* death16 = (unsigned short*)(wsb + 196608); // alias, later
    unsigned short* et      = (unsigned short*)(wsb + 262144);
    float*          wsum    = (float*)(wsb + 786432);
    float*          pooled  = (float*)(wsb + 786496);

    hipLaunchKernelGGL(filt_kernel,  dim3(N_NODES / 8), dim3(256), 0, stream,
                       X, W1, b1, W2, b2, filtT);
    hipLaunchKernelGGL(wsum_kernel,  dim3(1), dim3(64), 0, stream, Wt, bt, wsum);
    hipLaunchKernelGGL(rank_kernel,  dim3(4 * 32), dim3(256), 0, stream,
                       filtT, pos16, order16);
    hipLaunchKernelGGL(etable_kernel, dim3(4 * 32), dim3(256), 0, stream,
                       order16, pos16, edge_dst, et);
    hipLaunchKernelGGL(persist_kernel, dim3(N_FILT), dim3(256), 0, stream,
                       et, pos16, death16);
    hipLaunchKernelGGL(pooled_kernel, dim3(N_NODES / 256), dim3(256), 0, stream,
                       pos16, death16, wsum, pooled);
    hipLaunchKernelGGL(out_kernel,   dim3(N_NODES), dim3(256), 0, stream,
                       X, Wr, br, pooled, (float*)d_out);
}